// Round 1
// baseline (483.100 us; speedup 1.0000x reference)
//
#include <hip/hip_runtime.h>
#include <cstddef>
#include <cstdint>

// ---------------------------------------------------------------------------
// SelfAttention: h = softmax(QK^T*scale - 1e9*mask) @ V, p also output.
// B=8, S=2048, F=D=512.
// R6: all four GEMMs ported to the 256x256 8-phase counted-vmcnt schedule
//     (T2 XOR-swizzle + T3/T4 + T5). Activations pre-converted to bf16 so
//     every GEMM stages via global_load_lds (16B). Workspace 113.5 MB
//     (bf16 X aliased with s_bf; X dead before QK^T writes scores).
// ---------------------------------------------------------------------------

typedef __bf16 bf16_t;
typedef __bf16 bf16x8 __attribute__((ext_vector_type(8)));
typedef float f32x4 __attribute__((ext_vector_type(4)));

#define AS1 __attribute__((address_space(1)))
#define AS3 __attribute__((address_space(3)))

__device__ __forceinline__ void gload_lds16(const void* g, void* l) {
  // async global->LDS, 16B/lane; LDS dst = wave-uniform base + lane*16
  __builtin_amdgcn_global_load_lds((AS1 void*)(g), (AS3 void*)(l), 16, 0, 0);
}

#define VM6 asm volatile("s_waitcnt vmcnt(6)" ::: "memory")
#define VM0 asm volatile("s_waitcnt vmcnt(0)" ::: "memory")

// LDS fragment reads. Region = [256 rows][64 cols] bf16, row stride 128B.
// In-row XOR swizzle: slot16B ^= (row&7). row&7 == lr&7 for all frags.
#define LDA_(par, q, m01, kk) \
  (*(const bf16x8*)(AsB + (par)*32768 + arow + (q)*4096 + (m01)*2048 + offk##kk))
#define LDB_(par, nf, kk) \
  (*(const bf16x8*)(BsB + (par)*32768 + brow + (nf)*2048 + offk##kk))

// One phase: {ds-read frags | stage 1 half-tile | [vmcnt] | bar | MFMA | bar}
#define PHASE(par, q, FIRST, STAGE_STMT, WAIT_STMT)                              \
  {                                                                              \
    if (FIRST) {                                                                 \
      _Pragma("unroll") for (int nf = 0; nf < 4; ++nf) {                         \
        br[nf][0] = LDB_(par, nf, 0);                                            \
        br[nf][1] = LDB_(par, nf, 1);                                            \
      }                                                                          \
    }                                                                            \
    bf16x8 a00 = LDA_(par, q, 0, 0), a01 = LDA_(par, q, 0, 1);                   \
    bf16x8 a10 = LDA_(par, q, 1, 0), a11 = LDA_(par, q, 1, 1);                   \
    STAGE_STMT;                                                                  \
    WAIT_STMT;                                                                   \
    __builtin_amdgcn_s_barrier();                                                \
    __builtin_amdgcn_s_setprio(1);                                               \
    _Pragma("unroll") for (int nf = 0; nf < 4; ++nf) {                           \
      acc[2*(q)][nf]   = __builtin_amdgcn_mfma_f32_16x16x32_bf16(a00, br[nf][0], acc[2*(q)][nf], 0, 0, 0);     \
      acc[2*(q)][nf]   = __builtin_amdgcn_mfma_f32_16x16x32_bf16(a01, br[nf][1], acc[2*(q)][nf], 0, 0, 0);     \
      acc[2*(q)+1][nf] = __builtin_amdgcn_mfma_f32_16x16x32_bf16(a10, br[nf][0], acc[2*(q)+1][nf], 0, 0, 0);   \
      acc[2*(q)+1][nf] = __builtin_amdgcn_mfma_f32_16x16x32_bf16(a11, br[nf][1], acc[2*(q)+1][nf], 0, 0, 0);   \
    }                                                                            \
    __builtin_amdgcn_s_setprio(0);                                               \
    __builtin_amdgcn_s_barrier();                                                \
  }

// C[M,N] = A[M,K] * B[N,K]^T, 256x256 tile, BK=64, 8 waves (2M x 4N),
// double-buffered K-tile regions (even/odd), 8-phase interleave,
// counted vmcnt(6) at phases 4 and 8 only.
// MODE 0: proj  (grid 256): m = id>>1 (stacked q;k rows), n = id&1; B selects
//         Wq^T/Wk^T by m_blk.
// MODE 1: QK^T  (grid 512): z = id&7 (batch->XCD), j = id>>3: m=j>>3, n=j&7.
// MODE 2: Vt    (grid 128): z = id&7, j = id>>3: m=j&1 (D), n=j>>1 (S).
// MODE 3: PV    (grid 128): z = id&7, j = id>>3: m=j>>1, n=j&1.
template <int MODE, bool OUT_BF16>
__global__ __launch_bounds__(512, 2) void gemm256(
    const bf16_t* __restrict__ A, const bf16_t* __restrict__ B, void* __restrict__ Cb,
    long sA, long sB, long sC, int ldA, int ldB, int ldC, int K) {
  __shared__ bf16_t As[2][16384];  // [dbuf][256*64]
  __shared__ bf16_t Bs[2][16384];
  const int tid = threadIdx.x;
  const int wave = tid >> 6, lane = tid & 63;
  const int wm = wave >> 2, wn = wave & 3;    // 2M x 4N waves
  const int lr = lane & 15, hi = lane >> 4;
  const int id = blockIdx.x;

  int z = 0, m_blk, n_blk;
  if constexpr (MODE == 0) {
    m_blk = (id >> 1) * 256; n_blk = (id & 1) * 256;
  } else if constexpr (MODE == 1) {
    z = id & 7; const int j = id >> 3; m_blk = (j >> 3) * 256; n_blk = (j & 7) * 256;
  } else if constexpr (MODE == 2) {
    z = id & 7; const int j = id >> 3; m_blk = (j & 1) * 256; n_blk = (j >> 1) * 256;
  } else {
    z = id & 7; const int j = id >> 3; m_blk = (j >> 1) * 256; n_blk = (j & 1) * 256;
  }

  const bf16_t* Ab = A + (size_t)z * sA + (size_t)m_blk * ldA;
  const bf16_t* Bp;
  if constexpr (MODE == 0)
    Bp = B + (m_blk >= 16384 ? (size_t)sB : 0) + (size_t)n_blk * ldB;
  else
    Bp = B + (size_t)z * sB + (size_t)n_blk * ldB;

  // Stage one 128x64 half-tile (2 x gload_lds per thread). LDS dest is
  // linear; the read-side XOR swizzle is pre-applied to the GLOBAL source
  // column (rule #21: both-sides-or-neither).
  auto STG = [&](int par, int kt, int isB, int h) {
    const bf16_t* src = isB ? Bp : Ab;
    const int ld = isB ? ldB : ldA;
    bf16_t* lds = (isB ? &Bs[par][0] : &As[par][0]) + h * 8192;
#pragma unroll
    for (int i = 0; i < 2; ++i) {
      const int c = i * 512 + tid;                  // chunk 0..1023
      const int r = c >> 3, cc = (c & 7) ^ (r & 7); // inverse swizzle on src
      gload_lds16(src + (size_t)(h * 128 + r) * ld + kt * 64 + cc * 8,
                  lds + i * 4096 + wave * 512);     // wave-uniform base
    }
  };

  f32x4 acc[8][4] = {};
  bf16x8 br[4][2];  // B frags cached per K-tile (loaded at phases 1/5)
  const char* AsB = (const char*)&As[0][0];
  const char* BsB = (const char*)&Bs[0][0];
  const int arow = wm * 16384 + lr * 128;  // bytes
  const int brow = wn * 8192 + lr * 128;
  const int swz = (lr & 7) << 4;
  const int offk0 = (hi * 16) ^ swz;
  const int offk1 = (64 + hi * 16) ^ swz;

  const int NITER = K >> 7;  // 2 K-tiles (BK=64) per iteration
  // prologue: K0 {B0,B1,A0,A1} + K1 {B0,B1,A0}; vmcnt(6) -> K0 landed.
  STG(0, 0, 1, 0); STG(0, 0, 1, 1); STG(0, 0, 0, 0); STG(0, 0, 0, 1);
  STG(1, 1, 1, 0); STG(1, 1, 1, 1); STG(1, 1, 0, 0);
  VM6;
  __builtin_amdgcn_s_barrier();

  for (int t = 0; t < NITER; ++t) {
    const bool pf = (t + 1 < NITER);
    const int k1 = 2 * t + 1, ka = 2 * t + 2, kb = 2 * t + 3;
    // phases 1-4: compute K-tile 2t (even region); 5-8: K-tile 2t+1 (odd).
    PHASE(0, 0, 1, { STG(1, k1, 0, 1); }, {});
    PHASE(0, 1, 0, { if (pf) STG(0, ka, 1, 0); }, {});
    PHASE(0, 2, 0, { if (pf) STG(0, ka, 1, 1); }, {});
    PHASE(0, 3, 0, { if (pf) STG(0, ka, 0, 0); }, { if (pf) VM6; else VM0; });
    PHASE(1, 0, 1, { if (pf) STG(0, ka, 0, 1); }, {});
    PHASE(1, 1, 0, { if (pf) STG(1, kb, 1, 0); }, {});
    PHASE(1, 2, 0, { if (pf) STG(1, kb, 1, 1); }, {});
    PHASE(1, 3, 0, { if (pf) STG(1, kb, 0, 0); }, { if (pf) VM6; });
  }

  // epilogue: C/D layout col = lane&15, row = (lane>>4)*4 + reg
  const int row0 = m_blk + wm * 128 + hi * 4;
  const int col0 = n_blk + wn * 64 + lr;
  if constexpr (OUT_BF16) {
    bf16_t* C = (bf16_t*)Cb + (size_t)z * sC;
#pragma unroll
    for (int mf = 0; mf < 8; ++mf)
#pragma unroll
      for (int nf = 0; nf < 4; ++nf)
#pragma unroll
        for (int tt = 0; tt < 4; ++tt)
          C[(size_t)(row0 + mf * 16 + tt) * ldC + col0 + nf * 16] = (bf16_t)acc[mf][nf][tt];
  } else {
    float* C = (float*)Cb + (size_t)z * sC;
#pragma unroll
    for (int mf = 0; mf < 8; ++mf)
#pragma unroll
      for (int nf = 0; nf < 4; ++nf)
#pragma unroll
        for (int tt = 0; tt < 4; ++tt)
          C[(size_t)(row0 + mf * 16 + tt) * ldC + col0 + nf * 16] = acc[mf][nf][tt];
  }
}

// fp32 -> bf16 convert of q_x,k_x,v_x into Xb[3][16384][512]. grid 12288x256.
__global__ void cvt3(const float* __restrict__ q, const float* __restrict__ k,
                     const float* __restrict__ v, bf16_t* __restrict__ out) {
  const int which = blockIdx.x >> 12;  // 4096 blocks per input
  const float* in = which == 0 ? q : (which == 1 ? k : v);
  const size_t off = ((size_t)(blockIdx.x & 4095) * 256 + threadIdx.x) * 8;
  f32x4 a = *(const f32x4*)(in + off);
  f32x4 b = *(const f32x4*)(in + off + 4);
  bf16x8 o;
#pragma unroll
  for (int j = 0; j < 4; ++j) { o[j] = (bf16_t)a[j]; o[4 + j] = (bf16_t)b[j]; }
  *(bf16x8*)(out + (size_t)which * 8388608 + off) = o;
}

// WT[z][d][f] = W_z[f][d], fp32 -> bf16. grid (16,16,3), block (32,8).
__global__ void prep_wt(const float* __restrict__ Wq, const float* __restrict__ Wk,
                        const float* __restrict__ Wv, bf16_t* __restrict__ WT) {
  __shared__ float tile[32][33];
  const int z = blockIdx.z;
  const float* W = z == 0 ? Wq : (z == 1 ? Wk : Wv);
  const int f0 = blockIdx.y * 32, d0 = blockIdx.x * 32;
  const int tx = threadIdx.x, ty = threadIdx.y;
#pragma unroll
  for (int i = 0; i < 32; i += 8) tile[ty + i][tx] = W[(size_t)(f0 + ty + i) * 512 + d0 + tx];
  __syncthreads();
  bf16_t* out = WT + (size_t)z * 512 * 512;
#pragma unroll
  for (int i = 0; i < 32; i += 8)
    out[(size_t)(d0 + ty + i) * 512 + f0 + tx] = (bf16_t)tile[tx][ty + i];
}

// p = softmax(s_bf*scale - 1e9*mask) per row of 2048. One 256-thr block per row.
// Reads bf16 raw scores; writes fp32 p (nontemporal, final output) + bf16 p
// in-place over the score buffer (consumed by the PV GEMM).
__global__ void softmax_mask(bf16_t* __restrict__ s_bf, const float* __restrict__ mask,
                             float* __restrict__ p) {
  constexpr int S = 2048;
  constexpr float scale = 0.04419417382415922f;  // 1/sqrt(512)
  const size_t row = blockIdx.x;
  bf16_t* sr = s_bf + row * S;
  float* pr = p + row * S;
  const float* mr = mask + row * S;
  const int t = threadIdx.x;
  const int c0 = t * 8;  // 8 contiguous cols per thread
  bf16x8 sv = *(const bf16x8*)&sr[c0];
  f32x4 m0 = *(const f32x4*)&mr[c0];
  f32x4 m1 = *(const f32x4*)&mr[c0 + 4];
  float l[8];
  float mx = -3.4e38f;
#pragma unroll
  for (int i = 0; i < 8; ++i) {
    float m = (i < 4) ? m0[i & 3] : m1[i & 3];
    float v = (float)sv[i] * scale + m * (-1e9f);
    l[i] = v;
    mx = fmaxf(mx, v);
  }
  __shared__ float red[8];
  for (int off = 32; off > 0; off >>= 1) mx = fmaxf(mx, __shfl_down(mx, off));
  const int wv = t >> 6, ln = t & 63;
  if (ln == 0) red[wv] = mx;
  __syncthreads();
  mx = fmaxf(fmaxf(red[0], red[1]), fmaxf(red[2], red[3]));
  float s = 0.f;
#pragma unroll
  for (int i = 0; i < 8; ++i) {
    float e = __expf(l[i] - mx);
    l[i] = e;
    s += e;
  }
  for (int off = 32; off > 0; off >>= 1) s += __shfl_down(s, off);
  if (ln == 0) red[4 + wv] = s;
  __syncthreads();
  s = red[4] + red[5] + red[6] + red[7];
  const float inv = 1.f / s;
  f32x4 o0, o1;
  bf16x8 ob;
#pragma unroll
  for (int i = 0; i < 8; ++i) {
    float v = l[i] * inv;
    if (i < 4) o0[i & 3] = v; else o1[i & 3] = v;
    ob[i] = (bf16_t)v;
  }
  __builtin_nontemporal_store(o0, (f32x4*)&pr[c0]);
  __builtin_nontemporal_store(o1, (f32x4*)&pr[c0 + 4]);
  *(bf16x8*)&sr[c0] = ob;  // in-place bf16 p for PV
}

extern "C" void kernel_launch(void* const* d_in, const int* in_sizes, int n_in,
                              void* d_out, int out_size, void* d_ws, size_t ws_size,
                              hipStream_t stream) {
  const int B = 8, S = 2048, F = 512, D = 512;
  const float* q_x = (const float*)d_in[0];
  const float* k_x = (const float*)d_in[1];
  const float* v_x = (const float*)d_in[2];
  const float* mask = (const float*)d_in[3];
  const float* Wq = (const float*)d_in[4];
  const float* Wk = (const float*)d_in[5];
  const float* Wv = (const float*)d_in[6];

  float* h_out = (float*)d_out;                 // [B,S,D]
  float* p_out = h_out + (size_t)B * S * D;     // [B,S,S]

  const size_t BSD = (size_t)B * S * D;         // 8388608
  const size_t DF = (size_t)D * F;              // 262144
  // ws: Q,K (2*BSD), Vt (BSD), WT (3*DF), then Xb (3*BSD) aliased with
  // s_bf (B*S*S): Xb dead before QK^T writes scores. Total 113.5 MB.
  bf16_t* Q = (bf16_t*)d_ws;
  bf16_t* Km = Q + BSD;
  bf16_t* Vt = Q + 2 * BSD;                     // [B][D][S]
  bf16_t* WT = Q + 3 * BSD;                     // [3][D][F]
  bf16_t* Xb = WT + 3 * DF;                     // [3][16384][512] bf16 x
  bf16_t* s_bf = Xb;                            // [B][S][S] raw scores -> p_bf

  // 1. W -> W^T bf16; x -> bf16
  prep_wt<<<dim3(16, 16, 3), dim3(32, 8), 0, stream>>>(Wq, Wk, Wv, WT);
  cvt3<<<dim3(12288), dim3(256), 0, stream>>>(q_x, k_x, v_x, Xb);

  // 2a. Q;K stacked projection: [32768,512] = Xb[q;k] @ W^T  (B by m-strip)
  gemm256<0, true><<<dim3(256), dim3(512), 0, stream>>>(
      Xb, WT, Q, 0, (long)DF, 0, F, F, D, F);

  // 2b. Vt[b][d][s] = Wv^T @ x_v^T (A = Wv^T, no batch; B = x_v bf16)
  gemm256<2, true><<<dim3(128), dim3(512), 0, stream>>>(
      WT + 2 * DF, Xb + 2 * BSD, Vt, 0, (long)((size_t)S * F),
      (long)((size_t)D * S), F, F, S, F);

  // 3. raw scores bf16: s_bf[b] = Q_b @ K_b^T  (batch->XCD)
  gemm256<1, true><<<dim3(512), dim3(512), 0, stream>>>(
      Q, Km, s_bf, (long)((size_t)S * D), (long)((size_t)S * D),
      (long)((size_t)S * S), D, D, S, D);

  // 4. masked softmax: fp32 p to d_out (nontemporal) + bf16 p in-place
  softmax_mask<<<dim3(B * S), dim3(256), 0, stream>>>(s_bf, mask, p_out);

  // 5. h[b] = p_b @ Vt_b^T  (batch->XCD)
  gemm256<3, false><<<dim3(128), dim3(512), 0, stream>>>(
      s_bf, Vt, h_out, (long)((size_t)S * S), (long)((size_t)D * S),
      (long)((size_t)S * D), S, S, D, S);
}

// Round 2
// 461.254 us; speedup vs baseline: 1.0474x; 1.0474x over previous
//
#include <hip/hip_runtime.h>
#include <cstddef>
#include <cstdint>

// ---------------------------------------------------------------------------
// SelfAttention: h = softmax(QK^T*scale - 1e9*mask) @ V, p also output.
// B=8, S=2048, F=D=512.
// R7: 256xBN 8-phase counted-vmcnt GEMM with RACE-FREE quarter-tile staging:
//     each 64-row quarter of a tile is staged >=1 barrier AFTER its last
//     ds_read (A q0/q2 last read ph1, q1/q3 ph3; B read ph0 only), so no
//     write can land in a region another wave is still reading. vmcnt(6)
//     (BN=256) / vmcnt(4) (BN=128) at phases 3/7 keeps the pipeline deep.
//     PV and Vt use BN=128 -> grid 256 (full machine, was 128 = half idle).
// ---------------------------------------------------------------------------

typedef __bf16 bf16_t;
typedef __bf16 bf16x8 __attribute__((ext_vector_type(8)));
typedef float f32x4 __attribute__((ext_vector_type(4)));

#define AS1 __attribute__((address_space(1)))
#define AS3 __attribute__((address_space(3)))

__device__ __forceinline__ void gload_lds16(const void* g, void* l) {
  // async global->LDS, 16B/lane; LDS dst = wave-uniform base + lane*16
  __builtin_amdgcn_global_load_lds((AS1 void*)(g), (AS3 void*)(l), 16, 0, 0);
}

#define VMW(n) asm volatile("s_waitcnt vmcnt(" #n ")" ::: "memory")
// steady-state counted wait: leaves the newer 6 (BN=256) / 4 (BN=128)
// quarter-loads in flight, drains the 8/6 belonging to the tile about to
// be consumed.
#define VMS do { if constexpr (NF == 4) VMW(6); else VMW(4); } while (0)
#define VM0 VMW(0)

#define MFMA(a, b, c) __builtin_amdgcn_mfma_f32_16x16x32_bf16(a, b, c, 0, 0, 0)

// LDS fragment reads. A region = [256][64] bf16 (32KB), B region = [BN][64].
// In-row XOR swizzle on the 16B slot: slot ^= (row & 7).
#define LDA_(par, q, m01, kk) \
  (*(const bf16x8*)(AsB + (par)*32768 + arow + (q)*4096 + (m01)*2048 + offk##kk))
#define LDB_(par, nf, kk) \
  (*(const bf16x8*)(BsB + (par)*BREG + brow + (nf)*2048 + offk##kk))

// One phase: {ds-read frags | stage quarters | [vmcnt] | bar | MFMA | bar}
#define PH(par, q, FIRST, STAGE_STMT, WAIT_STMT)                                 \
  {                                                                              \
    if (FIRST) {                                                                 \
      _Pragma("unroll") for (int nf = 0; nf < NF; ++nf) {                        \
        br[nf][0] = LDB_(par, nf, 0);                                            \
        br[nf][1] = LDB_(par, nf, 1);                                            \
      }                                                                          \
    }                                                                            \
    bf16x8 a00 = LDA_(par, q, 0, 0), a01 = LDA_(par, q, 0, 1);                   \
    bf16x8 a10 = LDA_(par, q, 1, 0), a11 = LDA_(par, q, 1, 1);                   \
    STAGE_STMT;                                                                  \
    WAIT_STMT;                                                                   \
    __builtin_amdgcn_s_barrier();                                                \
    __builtin_amdgcn_s_setprio(1);                                               \
    _Pragma("unroll") for (int nf = 0; nf < NF; ++nf) {                          \
      acc[2*(q)][nf]   = MFMA(a00, br[nf][0], acc[2*(q)][nf]);                   \
      acc[2*(q)][nf]   = MFMA(a01, br[nf][1], acc[2*(q)][nf]);                   \
      acc[2*(q)+1][nf] = MFMA(a10, br[nf][0], acc[2*(q)+1][nf]);                 \
      acc[2*(q)+1][nf] = MFMA(a11, br[nf][1], acc[2*(q)+1][nf]);                 \
    }                                                                            \
    __builtin_amdgcn_s_setprio(0);                                               \
    __builtin_amdgcn_s_barrier();                                                \
  }

// C[M,N] = A[M,K] * B[N,K]^T. BM=256, BN in {256,128}, BK=64, 8 waves (2Mx4N),
// 2 K-tiles per iter (even/odd LDS regions), 8 phases/iter.
// Stage schedule per iter t (tiles E=2t, O=2t+1; prefetch E2=2t+2, O2=2t+3):
//   ph0: O A-q1,q3          (O A q1/q3 last read prev ph6,7 -> safe)
//   ph1: E2 B-q0,q1         (E B read ph0 only)
//   ph2: E2 B-q2,q3 [BN256] | E2 A-q0,q2 [BN128]   (E A q0/q2 read ph0,1)
//   ph3: E2 A-q0,q2 [BN256] | -        ; WAIT: odd tile landed (VMS / VM0)
//   ph4: E2 A-q1,q3         (E A q1/q3 read ph2,3)
//   ph5: O2 B-q0,q1         (O B read ph4 only)
//   ph6: O2 B-q2,q3 [BN256] | O2 A-q0,q2 [BN128]   (O A q0/q2 read ph4,5)
//   ph7: O2 A-q0,q2 [BN256] | -        ; WAIT: even tile landed (VMS)
// MODE 0: proj (grid 256): m=id>>1 (stacked q;k), n=id&1; B selects Wq/Wk^T.
// MODE 1: QK^T (grid 512): z=id&7 (batch->XCD), j=id>>3: m=j>>3, n=j&7.
// MODE 2: Vt   (grid 256): z=id&7, j=id>>3 (0..31): m=(j&1), n=j>>1.
// MODE 3: PV   (grid 256): z=id&7, j=id>>3 (0..31): n=j&3 (fastest: 4 blocks
//         sharing a p row-strip land consecutively on batch's XCD), m=j>>2.
template <int MODE, int BN, bool OUT_BF16>
__global__ __launch_bounds__(512, 2) void gemm256(
    const bf16_t* __restrict__ A, const bf16_t* __restrict__ B, void* __restrict__ Cb,
    long sA, long sB, long sC, int ldA, int ldB, int ldC, int K) {
  constexpr int NF = BN / 64;        // n-frags per wave (4 or 2)
  constexpr int BREG = BN * 128;     // B region bytes
  __shared__ bf16_t As[2][16384];
  __shared__ bf16_t Bs[2][BN * 64];
  const int tid = threadIdx.x;
  const int wave = tid >> 6, lane = tid & 63;
  const int wm = wave >> 2, wn = wave & 3;  // 2M x 4N waves
  const int lr = lane & 15, hi = lane >> 4;
  const int id = blockIdx.x;

  int z = 0, m_blk, n_blk;
  if constexpr (MODE == 0) {
    m_blk = (id >> 1) * 256; n_blk = (id & 1) * 256;
  } else if constexpr (MODE == 1) {
    z = id & 7; const int j = id >> 3; m_blk = (j >> 3) * 256; n_blk = (j & 7) * 256;
  } else if constexpr (MODE == 2) {
    z = id & 7; const int j = id >> 3; m_blk = (j & 1) * 256; n_blk = (j >> 1) * 128;
  } else {
    z = id & 7; const int j = id >> 3; m_blk = (j >> 2) * 256; n_blk = (j & 3) * 128;
  }

  const bf16_t* Ab = A + (size_t)z * sA + (size_t)m_blk * ldA;
  const bf16_t* Bp;
  if constexpr (MODE == 0)
    Bp = B + (m_blk >= 16384 ? (size_t)sB : 0) + (size_t)n_blk * ldB;
  else
    Bp = B + (size_t)z * sB + (size_t)n_blk * ldB;

  // Stage one 64-row quarter (1 gload/thread = 1 vmcnt unit). LDS dest is
  // linear; read-side XOR swizzle pre-applied to the GLOBAL source column
  // (rule #21). Row within quarter r = tid>>3; slot = (tid&7) ^ (r&7).
  auto STGA = [&](int par, int kt, int qi) {
    const int r = tid >> 3, cc = (tid & 7) ^ (r & 7);
    gload_lds16(Ab + (size_t)(qi * 64 + r) * ldA + kt * 64 + cc * 8,
                &As[par][qi * 4096 + wave * 512]);
  };
  auto STGB = [&](int par, int kt, int qi) {
    const int r = tid >> 3, cc = (tid & 7) ^ (r & 7);
    gload_lds16(Bp + (size_t)(qi * 64 + r) * ldB + kt * 64 + cc * 8,
                &Bs[par][qi * 4096 + wave * 512]);
  };

  f32x4 acc[8][NF] = {};
  bf16x8 br[NF][2];  // B frags cached per K-tile (loaded at ph0/ph4)
  const char* AsB = (const char*)&As[0][0];
  const char* BsB = (const char*)&Bs[0][0];
  const int arow = wm * 16384 + lr * 128;      // bytes
  const int brow = wn * NF * 2048 + lr * 128;  // bytes
  const int swz = (lr & 7) << 4;
  const int offk0 = (hi * 16) ^ swz;
  const int offk1 = (64 + hi * 16) ^ swz;

  const int NITER = K >> 7;  // 2 K-tiles (BK=64) per iteration; NITER >= 2
  // prologue: tile0 fully (B then A), tile1 {B*, A-q0, A-q2}; drain tile0.
  if constexpr (NF == 4) { STGB(0, 0, 0); STGB(0, 0, 1); STGB(0, 0, 2); STGB(0, 0, 3); }
  else                   { STGB(0, 0, 0); STGB(0, 0, 1); }
  STGA(0, 0, 0); STGA(0, 0, 1); STGA(0, 0, 2); STGA(0, 0, 3);
  if constexpr (NF == 4) { STGB(1, 1, 0); STGB(1, 1, 1); STGB(1, 1, 2); STGB(1, 1, 3); }
  else                   { STGB(1, 1, 0); STGB(1, 1, 1); }
  STGA(1, 1, 0); STGA(1, 1, 2);
  VMS;
  __builtin_amdgcn_s_barrier();

  for (int t = 0; t < NITER; ++t) {
    const bool pf = (t + 1 < NITER);
    const int ko = 2 * t + 1, ka = 2 * t + 2, kb = 2 * t + 3;
    PH(0, 0, 1, { STGA(1, ko, 1); STGA(1, ko, 3); }, {});
    PH(0, 1, 0, { if (pf) { STGB(0, ka, 0); STGB(0, ka, 1); } }, {});
    if constexpr (NF == 4) {
      PH(0, 2, 0, { if (pf) { STGB(0, ka, 2); STGB(0, ka, 3); } }, {});
      PH(0, 3, 0, { if (pf) { STGA(0, ka, 0); STGA(0, ka, 2); } },
         { if (pf) VMS; else VM0; });
    } else {
      PH(0, 2, 0, { if (pf) { STGA(0, ka, 0); STGA(0, ka, 2); } }, {});
      PH(0, 3, 0, {}, { if (pf) VMS; else VM0; });
    }
    PH(1, 0, 1, { if (pf) { STGA(0, ka, 1); STGA(0, ka, 3); } }, {});
    PH(1, 1, 0, { if (pf) { STGB(1, kb, 0); STGB(1, kb, 1); } }, {});
    if constexpr (NF == 4) {
      PH(1, 2, 0, { if (pf) { STGB(1, kb, 2); STGB(1, kb, 3); } }, {});
      PH(1, 3, 0, { if (pf) { STGA(1, kb, 0); STGA(1, kb, 2); } }, { if (pf) VMS; });
    } else {
      PH(1, 2, 0, { if (pf) { STGA(1, kb, 0); STGA(1, kb, 2); } }, {});
      PH(1, 3, 0, {}, { if (pf) VMS; });
    }
  }

  // epilogue: C/D layout col = lane&15, row = (lane>>4)*4 + reg
  const int row0 = m_blk + wm * 128 + hi * 4;
  const int col0 = n_blk + wn * (16 * NF) + lr;
  if constexpr (OUT_BF16) {
    bf16_t* C = (bf16_t*)Cb + (size_t)z * sC;
#pragma unroll
    for (int mf = 0; mf < 8; ++mf)
#pragma unroll
      for (int nf = 0; nf < NF; ++nf)
#pragma unroll
        for (int tt = 0; tt < 4; ++tt)
          C[(size_t)(row0 + mf * 16 + tt) * ldC + col0 + nf * 16] = (bf16_t)acc[mf][nf][tt];
  } else {
    float* C = (float*)Cb + (size_t)z * sC;
#pragma unroll
    for (int mf = 0; mf < 8; ++mf)
#pragma unroll
      for (int nf = 0; nf < NF; ++nf)
#pragma unroll
        for (int tt = 0; tt < 4; ++tt)
          C[(size_t)(row0 + mf * 16 + tt) * ldC + col0 + nf * 16] = acc[mf][nf][tt];
  }
}

// fp32 -> bf16 convert of q_x,k_x,v_x into Xb[3][16384][512]. grid 12288x256.
__global__ void cvt3(const float* __restrict__ q, const float* __restrict__ k,
                     const float* __restrict__ v, bf16_t* __restrict__ out) {
  const int which = blockIdx.x >> 12;  // 4096 blocks per input
  const float* in = which == 0 ? q : (which == 1 ? k : v);
  const size_t off = ((size_t)(blockIdx.x & 4095) * 256 + threadIdx.x) * 8;
  f32x4 a = *(const f32x4*)(in + off);
  f32x4 b = *(const f32x4*)(in + off + 4);
  bf16x8 o;
#pragma unroll
  for (int j = 0; j < 4; ++j) { o[j] = (bf16_t)a[j]; o[4 + j] = (bf16_t)b[j]; }
  *(bf16x8*)(out + (size_t)which * 8388608 + off) = o;
}

// WT[z][d][f] = W_z[f][d], fp32 -> bf16. grid (16,16,3), block (32,8).
__global__ void prep_wt(const float* __restrict__ Wq, const float* __restrict__ Wk,
                        const float* __restrict__ Wv, bf16_t* __restrict__ WT) {
  __shared__ float tile[32][33];
  const int z = blockIdx.z;
  const float* W = z == 0 ? Wq : (z == 1 ? Wk : Wv);
  const int f0 = blockIdx.y * 32, d0 = blockIdx.x * 32;
  const int tx = threadIdx.x, ty = threadIdx.y;
#pragma unroll
  for (int i = 0; i < 32; i += 8) tile[ty + i][tx] = W[(size_t)(f0 + ty + i) * 512 + d0 + tx];
  __syncthreads();
  bf16_t* out = WT + (size_t)z * 512 * 512;
#pragma unroll
  for (int i = 0; i < 32; i += 8)
    out[(size_t)(d0 + ty + i) * 512 + f0 + tx] = (bf16_t)tile[tx][ty + i];
}

// p = softmax(s_bf*scale - 1e9*mask) per row of 2048. One 256-thr block per row.
// Reads bf16 raw scores; writes fp32 p (nontemporal, final output) + bf16 p
// in-place over the score buffer (consumed by the PV GEMM). Mask is streamed
// once -> nontemporal loads (don't evict s/p from L2).
__global__ void softmax_mask(bf16_t* __restrict__ s_bf, const float* __restrict__ mask,
                             float* __restrict__ p) {
  constexpr int S = 2048;
  constexpr float scale = 0.04419417382415922f;  // 1/sqrt(512)
  const size_t row = blockIdx.x;
  bf16_t* sr = s_bf + row * S;
  float* pr = p + row * S;
  const float* mr = mask + row * S;
  const int t = threadIdx.x;
  const int c0 = t * 8;  // 8 contiguous cols per thread
  bf16x8 sv = *(const bf16x8*)&sr[c0];
  f32x4 m0 = __builtin_nontemporal_load((const f32x4*)&mr[c0]);
  f32x4 m1 = __builtin_nontemporal_load((const f32x4*)&mr[c0 + 4]);
  float l[8];
  float mx = -3.4e38f;
#pragma unroll
  for (int i = 0; i < 8; ++i) {
    float m = (i < 4) ? m0[i & 3] : m1[i & 3];
    float v = (float)sv[i] * scale + m * (-1e9f);
    l[i] = v;
    mx = fmaxf(mx, v);
  }
  __shared__ float red[8];
  for (int off = 32; off > 0; off >>= 1) mx = fmaxf(mx, __shfl_down(mx, off));
  const int wv = t >> 6, ln = t & 63;
  if (ln == 0) red[wv] = mx;
  __syncthreads();
  mx = fmaxf(fmaxf(red[0], red[1]), fmaxf(red[2], red[3]));
  float s = 0.f;
#pragma unroll
  for (int i = 0; i < 8; ++i) {
    float e = __expf(l[i] - mx);
    l[i] = e;
    s += e;
  }
  for (int off = 32; off > 0; off >>= 1) s += __shfl_down(s, off);
  if (ln == 0) red[4 + wv] = s;
  __syncthreads();
  s = red[4] + red[5] + red[6] + red[7];
  const float inv = 1.f / s;
  f32x4 o0, o1;
  bf16x8 ob;
#pragma unroll
  for (int i = 0; i < 8; ++i) {
    float v = l[i] * inv;
    if (i < 4) o0[i & 3] = v; else o1[i & 3] = v;
    ob[i] = (bf16_t)v;
  }
  __builtin_nontemporal_store(o0, (f32x4*)&pr[c0]);
  __builtin_nontemporal_store(o1, (f32x4*)&pr[c0 + 4]);
  *(bf16x8*)&sr[c0] = ob;  // in-place bf16 p for PV
}

extern "C" void kernel_launch(void* const* d_in, const int* in_sizes, int n_in,
                              void* d_out, int out_size, void* d_ws, size_t ws_size,
                              hipStream_t stream) {
  const int B = 8, S = 2048, F = 512, D = 512;
  const float* q_x = (const float*)d_in[0];
  const float* k_x = (const float*)d_in[1];
  const float* v_x = (const float*)d_in[2];
  const float* mask = (const float*)d_in[3];
  const float* Wq = (const float*)d_in[4];
  const float* Wk = (const float*)d_in[5];
  const float* Wv = (const float*)d_in[6];

  float* h_out = (float*)d_out;                 // [B,S,D]
  float* p_out = h_out + (size_t)B * S * D;     // [B,S,S]

  const size_t BSD = (size_t)B * S * D;         // 8388608
  const size_t DF = (size_t)D * F;              // 262144
  // ws: Q,K (2*BSD), Vt (BSD), WT (3*DF), then Xb (3*BSD) aliased with
  // s_bf (B*S*S): Xb dead before QK^T writes scores. ~119 MB.
  bf16_t* Q = (bf16_t*)d_ws;
  bf16_t* Km = Q + BSD;
  bf16_t* Vt = Q + 2 * BSD;                     // [B][D][S]
  bf16_t* WT = Q + 3 * BSD;                     // [3][D][F]
  bf16_t* Xb = WT + 3 * DF;                     // [3][16384][512] bf16 x
  bf16_t* s_bf = Xb;                            // [B][S][S] raw scores -> p_bf

  // 1. W -> W^T bf16; x -> bf16
  prep_wt<<<dim3(16, 16, 3), dim3(32, 8), 0, stream>>>(Wq, Wk, Wv, WT);
  cvt3<<<dim3(12288), dim3(256), 0, stream>>>(q_x, k_x, v_x, Xb);

  // 2a. Q;K stacked projection: [32768,512] = Xb[q;k] @ W^T
  gemm256<0, 256, true><<<dim3(256), dim3(512), 0, stream>>>(
      Xb, WT, Q, 0, (long)DF, 0, F, F, D, F);

  // 2b. Vt[b][d][s] = Wv^T @ x_v^T (A = Wv^T, no batch; B = x_v bf16)
  gemm256<2, 128, true><<<dim3(256), dim3(512), 0, stream>>>(
      WT + 2 * DF, Xb + 2 * BSD, Vt, 0, (long)((size_t)S * F),
      (long)((size_t)D * S), F, F, S, F);

  // 3. raw scores bf16: s_bf[b] = Q_b @ K_b^T  (batch->XCD)
  gemm256<1, 256, true><<<dim3(512), dim3(512), 0, stream>>>(
      Q, Km, s_bf, (long)((size_t)S * D), (long)((size_t)S * D),
      (long)((size_t)S * S), D, D, S, D);

  // 4. masked softmax: fp32 p to d_out (nontemporal) + bf16 p in-place
  softmax_mask<<<dim3(B * S), dim3(256), 0, stream>>>(s_bf, mask, p_out);

  // 5. h[b] = p_b @ Vt_b^T  (batch->XCD, BN=128, full machine)
  gemm256<3, 128, false><<<dim3(256), dim3(512), 0, stream>>>(
      s_bf, Vt, h_out, (long)((size_t)S * S), (long)((size_t)D * S),
      (long)((size_t)S * D), S, S, D, S);
}

// Round 7
// 432.894 us; speedup vs baseline: 1.1160x; 1.0655x over previous
//
#include <hip/hip_runtime.h>
#include <cstddef>
#include <cstdint>

// ---------------------------------------------------------------------------
// SelfAttention: h = softmax(QK^T*scale - 1e9*mask) @ V, p also output.
// B=8, S=2048, F=D=512.
// R9: de-risk after 3 failed rounds (2x acquisition timeout, 1x container
//     death on the cooperative mega-kernel). Back to the PROVEN R7 multi-
//     dispatch structure (461us), repackaged:
//       K1 prep: cvt x->bf16 + W->W^T bf16 (merged, was 2 dispatches)
//       K2 proj(BN256,NF4) + Vt(BN128,NF2) merged via runtime branch
//       K3 QK^T (BN256, batch->XCD)
//       K4 masked softmax (mask applied in fp32 - bf16 mask-fusion is a
//          correctness trap, see journal)
//       K5 PV (BN128)
//     K-loop = R7's verified race-free quarter-stage 8-phase counted-vmcnt
//     schedule, unchanged. 7 -> 5 dispatches; no cooperative launch.
// ---------------------------------------------------------------------------

typedef __bf16 bf16_t;
typedef __bf16 bf16x8 __attribute__((ext_vector_type(8)));
typedef float f32x4 __attribute__((ext_vector_type(4)));

#define AS1 __attribute__((address_space(1)))
#define AS3 __attribute__((address_space(3)))

__device__ __forceinline__ void gload_lds16(const void* g, void* l) {
  // async global->LDS, 16B/lane; LDS dst = wave-uniform base + lane*16
  __builtin_amdgcn_global_load_lds((AS1 void*)(g), (AS3 void*)(l), 16, 0, 0);
}

#define VMW(n) asm volatile("s_waitcnt vmcnt(" #n ")" ::: "memory")
#define VMS do { if (NF == 4) VMW(6); else VMW(4); } while (0)
#define VM0 VMW(0)

#define MFMA_(a, b, c) __builtin_amdgcn_mfma_f32_16x16x32_bf16(a, b, c, 0, 0, 0)

// LDS fragment reads (byte offsets). A region 32KB each par, B region BREG.
// In-row XOR swizzle on the 16B slot: slot ^= (row & 7).
#define LDA_(par, q, m01, kk) \
  (*(const bf16x8*)(AsB + (par)*32768 + arow + (q)*4096 + (m01)*2048 + offk##kk))
#define LDB_(par, nf, kk) \
  (*(const bf16x8*)(BsB + (par)*BREG + brow + (nf)*2048 + offk##kk))

// One phase: {ds-read frags | stage quarters | [vmcnt] | bar | MFMA | bar}
#define PH(par, q, FIRST, STAGE_STMT, WAIT_STMT)                                 \
  {                                                                              \
    if (FIRST) {                                                                 \
      _Pragma("unroll") for (int nf = 0; nf < NF; ++nf) {                        \
        br[nf][0] = LDB_(par, nf, 0);                                            \
        br[nf][1] = LDB_(par, nf, 1);                                            \
      }                                                                          \
    }                                                                            \
    bf16x8 a00 = LDA_(par, q, 0, 0), a01 = LDA_(par, q, 0, 1);                   \
    bf16x8 a10 = LDA_(par, q, 1, 0), a11 = LDA_(par, q, 1, 1);                   \
    STAGE_STMT;                                                                  \
    WAIT_STMT;                                                                   \
    __builtin_amdgcn_s_barrier();                                                \
    __builtin_amdgcn_s_setprio(1);                                               \
    _Pragma("unroll") for (int nf = 0; nf < NF; ++nf) {                          \
      acc[2*(q)][nf]   = MFMA_(a00, br[nf][0], acc[2*(q)][nf]);                  \
      acc[2*(q)][nf]   = MFMA_(a01, br[nf][1], acc[2*(q)][nf]);                  \
      acc[2*(q)+1][nf] = MFMA_(a10, br[nf][0], acc[2*(q)+1][nf]);                \
      acc[2*(q)+1][nf] = MFMA_(a11, br[nf][1], acc[2*(q)+1][nf]);                \
    }                                                                            \
    __builtin_amdgcn_s_setprio(0);                                               \
    __builtin_amdgcn_s_barrier();                                                \
  }

// One 256xBN output tile of C = A[256,K] * B[BN,K]^T (R7 schedule verbatim).
// Race-free quarter staging: A q0/q2 last ds_read in phases 0-1, staged in
// phase 2+ (>=1 barrier later); A q1/q3 last read phases 2-3, staged next
// phase 0; B read phase 0/4 only. vmcnt ledger verified for NF=2 and NF=4.
template <int NF, bool OUT_BF16>
__device__ __forceinline__ void gemm_tile(
    const bf16_t* __restrict__ Ab, const bf16_t* __restrict__ Bp,
    void* __restrict__ Cp, int ldA, int ldB, int ldC, int K, char* smem) {
  constexpr int BREG = NF * 64 * 128;  // B region bytes (NF2:16K, NF4:32K)
  const int tid = threadIdx.x;
  const int wave = tid >> 6, lane = tid & 63;
  const int wm = wave >> 2, wn = wave & 3;  // 2M x 4N waves
  const int lr = lane & 15, hi = lane >> 4;
  bf16_t* AsE = (bf16_t*)smem;              // 2 x 16384 elems
  bf16_t* BsE = (bf16_t*)(smem + 65536);    // 2 x BREG/2 elems

  auto STGA = [&](int par, int kt, int qi) {
    const int r = tid >> 3, cc = (tid & 7) ^ (r & 7);
    gload_lds16(Ab + (size_t)(qi * 64 + r) * ldA + kt * 64 + cc * 8,
                AsE + par * 16384 + qi * 4096 + wave * 512);
  };
  auto STGB = [&](int par, int kt, int qi) {
    const int r = tid >> 3, cc = (tid & 7) ^ (r & 7);
    gload_lds16(Bp + (size_t)(qi * 64 + r) * ldB + kt * 64 + cc * 8,
                BsE + par * (BREG / 2) + qi * 4096 + wave * 512);
  };

  f32x4 acc[8][NF] = {};
  bf16x8 br[NF][2];
  const char* AsB = smem;
  const char* BsB = smem + 65536;
  const int arow = wm * 16384 + lr * 128;      // bytes
  const int brow = wn * NF * 2048 + lr * 128;  // bytes
  const int swz = (lr & 7) << 4;
  const int offk0 = (hi * 16) ^ swz;
  const int offk1 = (64 + hi * 16) ^ swz;

  const int NITER = K >> 7;  // 2 K-tiles (BK=64) per iteration
  if constexpr (NF == 4) { STGB(0,0,0); STGB(0,0,1); STGB(0,0,2); STGB(0,0,3); }
  else                   { STGB(0,0,0); STGB(0,0,1); }
  STGA(0,0,0); STGA(0,0,1); STGA(0,0,2); STGA(0,0,3);
  if constexpr (NF == 4) { STGB(1,1,0); STGB(1,1,1); STGB(1,1,2); STGB(1,1,3); }
  else                   { STGB(1,1,0); STGB(1,1,1); }
  STGA(1,1,0); STGA(1,1,2);
  VMS;
  __builtin_amdgcn_s_barrier();

  for (int t = 0; t < NITER; ++t) {
    const bool pf = (t + 1 < NITER);
    const int ko = 2*t + 1, ka = 2*t + 2, kb = 2*t + 3;
    PH(0, 0, 1, { STGA(1, ko, 1); STGA(1, ko, 3); }, {});
    PH(0, 1, 0, { if (pf) { STGB(0, ka, 0); STGB(0, ka, 1); } }, {});
    if constexpr (NF == 4) {
      PH(0, 2, 0, { if (pf) { STGB(0, ka, 2); STGB(0, ka, 3); } }, {});
      PH(0, 3, 0, { if (pf) { STGA(0, ka, 0); STGA(0, ka, 2); } },
         { if (pf) VMS; else VM0; });
    } else {
      PH(0, 2, 0, { if (pf) { STGA(0, ka, 0); STGA(0, ka, 2); } }, {});
      PH(0, 3, 0, {}, { if (pf) VMS; else VM0; });
    }
    PH(1, 0, 1, { if (pf) { STGA(0, ka, 1); STGA(0, ka, 3); } }, {});
    PH(1, 1, 0, { if (pf) { STGB(1, kb, 0); STGB(1, kb, 1); } }, {});
    if constexpr (NF == 4) {
      PH(1, 2, 0, { if (pf) { STGB(1, kb, 2); STGB(1, kb, 3); } }, {});
      PH(1, 3, 0, { if (pf) { STGA(1, kb, 0); STGA(1, kb, 2); } }, { if (pf) VMS; });
    } else {
      PH(1, 2, 0, { if (pf) { STGA(1, kb, 0); STGA(1, kb, 2); } }, {});
      PH(1, 3, 0, {}, { if (pf) VMS; });
    }
  }

  // epilogue: C/D layout col = lane&15, row = (lane>>4)*4 + reg
  const int row0 = wm * 128 + hi * 4;
  const int col0 = wn * (16 * NF) + lr;
  if constexpr (OUT_BF16) {
    bf16_t* C = (bf16_t*)Cp;
#pragma unroll
    for (int mf = 0; mf < 8; ++mf)
#pragma unroll
      for (int nf = 0; nf < NF; ++nf)
#pragma unroll
        for (int tt = 0; tt < 4; ++tt)
          C[(size_t)(row0 + mf * 16 + tt) * ldC + col0 + nf * 16] = (bf16_t)acc[mf][nf][tt];
  } else {
    float* C = (float*)Cp;
#pragma unroll
    for (int mf = 0; mf < 8; ++mf)
#pragma unroll
      for (int nf = 0; nf < NF; ++nf)
#pragma unroll
        for (int tt = 0; tt < 4; ++tt)
          C[(size_t)(row0 + mf * 16 + tt) * ldC + col0 + nf * 16] = acc[mf][nf][tt];
  }
}

// ---------------------------------------------------------------------------
// K1: x fp32->bf16 (blocks 0..12287) + W -> W^T bf16 (blocks 12288..13055).
// ---------------------------------------------------------------------------
__global__ void prep(const float* __restrict__ qx, const float* __restrict__ kx,
                     const float* __restrict__ vx, const float* __restrict__ Wq,
                     const float* __restrict__ Wk, const float* __restrict__ Wv,
                     bf16_t* __restrict__ Xb, bf16_t* __restrict__ WT) {
  __shared__ float tile[32][33];
  const int bid = blockIdx.x, tid = threadIdx.x;
  if (bid < 12288) {
    const int which = bid >> 12;
    const float* in = which == 0 ? qx : (which == 1 ? kx : vx);
    const size_t off = ((size_t)(bid & 4095) * 256 + tid) * 8;
    f32x4 a = *(const f32x4*)(in + off);
    f32x4 b = *(const f32x4*)(in + off + 4);
    bf16x8 o;
#pragma unroll
    for (int j = 0; j < 4; ++j) { o[j] = (bf16_t)a[j]; o[4 + j] = (bf16_t)b[j]; }
    *(bf16x8*)(Xb + (size_t)which * 8388608 + off) = o;
  } else {
    const int w = bid - 12288;                 // 0..767
    const int zz = w >> 8, tj = w & 255;
    const float* W = zz == 0 ? Wq : (zz == 1 ? Wk : Wv);
    const int f0 = (tj >> 4) * 32, d0 = (tj & 15) * 32;
    const int tx = tid & 31, ty = tid >> 5;    // 32 x 8
#pragma unroll
    for (int i = 0; i < 32; i += 8)
      tile[ty + i][tx] = W[(size_t)(f0 + ty + i) * 512 + d0 + tx];
    __syncthreads();
    bf16_t* out = WT + (size_t)zz * 262144;
#pragma unroll
    for (int i = 0; i < 32; i += 8)
      out[(size_t)(d0 + ty + i) * 512 + f0 + tx] = (bf16_t)tile[tx][ty + i];
  }
}

// ---------------------------------------------------------------------------
// K2: blocks 0..255 proj Q;K (BN256); blocks 256..511 Vt (BN128).
// ---------------------------------------------------------------------------
__global__ __launch_bounds__(512, 2) void projvt(
    const bf16_t* __restrict__ Xb, const bf16_t* __restrict__ WT,
    bf16_t* __restrict__ Q, bf16_t* __restrict__ Vt) {
  __shared__ __align__(16) char smem[131072];
  const int bid = blockIdx.x;
  if (bid < 256) {  // proj: m 0..127 (stacked q;k rows), n 0..1 (BN=256)
    const int m_blk = (bid >> 1) * 256, n_blk = (bid & 1) * 256;
    const bf16_t* Ab = Xb + (size_t)m_blk * 512;
    const bf16_t* Bp = WT + (m_blk >= 16384 ? (size_t)262144 : 0) + (size_t)n_blk * 512;
    bf16_t* Cp = Q + (size_t)m_blk * 512 + n_blk;
    gemm_tile<4, true>(Ab, Bp, Cp, 512, 512, 512, 512, smem);
  } else {          // Vt: z 0..7, mq 0..1 (D), nq 0..15 (S), BN=128
    const int l = bid - 256, zz = l & 7, jj = l >> 3;
    const int mq = jj & 1, nq = jj >> 1;
    const bf16_t* Ab = WT + (size_t)2 * 262144 + (size_t)(mq * 256) * 512;
    const bf16_t* Bp = Xb + (size_t)2 * 8388608 + (size_t)zz * (2048 * 512) +
                       (size_t)(nq * 128) * 512;
    bf16_t* Cp = Vt + (size_t)zz * (512 * 2048) + (size_t)(mq * 256) * 2048 + nq * 128;
    gemm_tile<2, true>(Ab, Bp, Cp, 512, 512, 2048, 512, smem);
  }
}

// ---------------------------------------------------------------------------
// K3: QK^T, BN=256, grid 512, batch->XCD (z = id&7).
// ---------------------------------------------------------------------------
__global__ __launch_bounds__(512, 2) void qkt(
    const bf16_t* __restrict__ Q, bf16_t* __restrict__ s_bf) {
  __shared__ __align__(16) char smem[131072];
  const int id = blockIdx.x;
  const int z = id & 7, j = id >> 3;
  const int m_blk = (j >> 3) * 256, n_blk = (j & 7) * 256;
  const bf16_t* Ab = Q + ((size_t)z * 2048 + m_blk) * 512;
  const bf16_t* Bp = Q + ((size_t)16384 + z * 2048 + n_blk) * 512;
  bf16_t* Cp = s_bf + (size_t)z * 2048 * 2048 + (size_t)m_blk * 2048 + n_blk;
  gemm_tile<4, true>(Ab, Bp, Cp, 512, 512, 2048, 512, smem);
}

// ---------------------------------------------------------------------------
// K4: p = softmax(s_bf*scale - 1e9*mask) per row; mask applied in FP32
// (required: -1e9*m gaps must stay exact; bf16 pre-fusion breaks softmax).
// Writes fp32 p (nontemporal, final output) + bf16 p in-place for PV.
// ---------------------------------------------------------------------------
__global__ void softmax_mask(bf16_t* __restrict__ s_bf, const float* __restrict__ mask,
                             float* __restrict__ p) {
  constexpr int S = 2048;
  constexpr float scale = 0.04419417382415922f;  // 1/sqrt(512)
  const size_t row = blockIdx.x;
  bf16_t* sr = s_bf + row * S;
  float* pr = p + row * S;
  const float* mr = mask + row * S;
  const int t = threadIdx.x;
  const int c0 = t * 8;  // 8 contiguous cols per thread
  bf16x8 sv = *(const bf16x8*)&sr[c0];
  f32x4 m0 = __builtin_nontemporal_load((const f32x4*)&mr[c0]);
  f32x4 m1 = __builtin_nontemporal_load((const f32x4*)&mr[c0 + 4]);
  float l[8];
  float mx = -3.4e38f;
#pragma unroll
  for (int i = 0; i < 8; ++i) {
    float m = (i < 4) ? m0[i & 3] : m1[i & 3];
    float v = (float)sv[i] * scale + m * (-1e9f);
    l[i] = v;
    mx = fmaxf(mx, v);
  }
  __shared__ float red[8];
  for (int off = 32; off > 0; off >>= 1) mx = fmaxf(mx, __shfl_down(mx, off));
  const int wv = t >> 6, ln = t & 63;
  if (ln == 0) red[wv] = mx;
  __syncthreads();
  mx = fmaxf(fmaxf(red[0], red[1]), fmaxf(red[2], red[3]));
  float s = 0.f;
#pragma unroll
  for (int i = 0; i < 8; ++i) {
    float e = __expf(l[i] - mx);
    l[i] = e;
    s += e;
  }
  for (int off = 32; off > 0; off >>= 1) s += __shfl_down(s, off);
  if (ln == 0) red[4 + wv] = s;
  __syncthreads();
  s = red[4] + red[5] + red[6] + red[7];
  const float inv = 1.f / s;
  f32x4 o0, o1;
  bf16x8 ob;
#pragma unroll
  for (int i = 0; i < 8; ++i) {
    float v = l[i] * inv;
    if (i < 4) o0[i & 3] = v; else o1[i & 3] = v;
    ob[i] = (bf16_t)v;
  }
  __builtin_nontemporal_store(o0, (f32x4*)&pr[c0]);
  __builtin_nontemporal_store(o1, (f32x4*)&pr[c0 + 4]);
  *(bf16x8*)&sr[c0] = ob;  // in-place bf16 p for PV
}

// ---------------------------------------------------------------------------
// K5: PV, BN=128, grid 256, batch->XCD; n fastest (L2 reuse of p strip).
// ---------------------------------------------------------------------------
__global__ __launch_bounds__(512, 2) void pv(
    const bf16_t* __restrict__ s_bf, const bf16_t* __restrict__ Vt,
    float* __restrict__ h_out) {
  __shared__ __align__(16) char smem[131072];
  const int id = blockIdx.x;
  const int z = id & 7, j = id >> 3;
  const int n_blk = (j & 3) * 128, m_blk = (j >> 2) * 256;
  const bf16_t* Ab = s_bf + (size_t)z * 2048 * 2048 + (size_t)m_blk * 2048;
  const bf16_t* Bp = Vt + (size_t)z * 512 * 2048 + (size_t)n_blk * 2048;
  float* Cp = h_out + (size_t)z * 2048 * 512 + (size_t)m_blk * 512 + n_blk;
  gemm_tile<2, false>(Ab, Bp, Cp, 2048, 2048, 512, 2048, smem);
}

extern "C" void kernel_launch(void* const* d_in, const int* in_sizes, int n_in,
                              void* d_out, int out_size, void* d_ws, size_t ws_size,
                              hipStream_t stream) {
  const float* q_x = (const float*)d_in[0];
  const float* k_x = (const float*)d_in[1];
  const float* v_x = (const float*)d_in[2];
  const float* mask = (const float*)d_in[3];
  const float* Wq = (const float*)d_in[4];
  const float* Wk = (const float*)d_in[5];
  const float* Wv = (const float*)d_in[6];

  float* h_out = (float*)d_out;                 // [B,S,D]
  float* p_out = h_out + (size_t)8 * 2048 * 512;  // [B,S,S]

  const size_t BSD = 8388608;                   // 8*2048*512
  const size_t DF = 262144;                     // 512*512
  // ws: Q;K (2*BSD), Vt (BSD), WT (3*DF), Xb (3*BSD) aliased with s_bf
  // (B*S*S): Xb dead before QK^T writes scores. ~114 MB.
  bf16_t* Q = (bf16_t*)d_ws;                    // [32768][512] (q;k rows)
  bf16_t* Vt = Q + 2 * BSD;                     // [8][512][2048]
  bf16_t* WT = Q + 3 * BSD;                     // [3][512][512]
  bf16_t* Xb = WT + 3 * DF;                     // [3][16384][512]
  bf16_t* s_bf = Xb;                            // [8][2048][2048] (alias)

  prep<<<dim3(13056), dim3(256), 0, stream>>>(q_x, k_x, v_x, Wq, Wk, Wv, Xb, WT);
  projvt<<<dim3(512), dim3(512), 0, stream>>>(Xb, WT, Q, Vt);
  qkt<<<dim3(512), dim3(512), 0, stream>>>(Q, s_bf);
  softmax_mask<<<dim3(16384), dim3(256), 0, stream>>>(s_bf, mask, p_out);
  pv<<<dim3(256), dim3(512), 0, stream>>>(s_bf, Vt, h_out);
}